// Round 7
// baseline (303.874 us; speedup 1.0000x reference)
//
#include <hip/hip_runtime.h>
#include <hip/hip_bf16.h>
#include <stdint.h>

#define B_ 16
#define L_ 2048
#define H_ 512
#define S_ 8
#define M_ 512
#define TG_ 64
#define NTOK (B_ * L_)     // 32768
#define FIVEH (5 * H_)     // 2560
#define FOURH (4 * H_)     // 2048

typedef __attribute__((ext_vector_type(4))) float f32x4;
typedef __attribute__((ext_vector_type(8))) short bf16x8;

__device__ __forceinline__ short f2bf(float f) {
  unsigned u = __builtin_bit_cast(unsigned, f);
  unsigned r = (u + 0x7FFFu + ((u >> 16) & 1u)) >> 16;
  return (short)r;
}

__device__ __forceinline__ void gload_lds16(const void* g, void* l) {
  __builtin_amdgcn_global_load_lds(
      (const __attribute__((address_space(1))) unsigned int*)g,
      (__attribute__((address_space(3))) unsigned int*)l, 16, 0, 0);
}

#define BAR __builtin_amdgcn_s_barrier()
#define LGKM0 do { asm volatile("s_waitcnt lgkmcnt(0)" ::: "memory"); \
                   __builtin_amdgcn_sched_barrier(0); } while (0)
#define VMW(n) asm volatile("s_waitcnt vmcnt(" #n ")" ::: "memory")
#define PRIO(p) __builtin_amdgcn_s_setprio(p)

#define MFMA16(qr, qc, bs) do {                                               \
    _Pragma("unroll") for (int fm = 0; fm < 4; ++fm)                          \
    _Pragma("unroll") for (int fn = 0; fn < 2; ++fn)                          \
    _Pragma("unroll") for (int ks = 0; ks < 2; ++ks)                          \
      acc[(qr)*4+fm][(qc)*2+fn] = __builtin_amdgcn_mfma_f32_16x16x32_bf16(    \
          a[fm][ks], bs[fn][ks], acc[(qr)*4+fm][(qc)*2+fn], 0, 0, 0); } while (0)

// ================= GEMM1 core: 256x256, BK=64, A 3-slot / B 2-slot, STATIC ==
// LDS (160 KiB exactly): A: slot*32768 (3 slots) ; B: 98304 + slot*32768 (2).
// Slot pattern period lcm(3,2)=6 -> 6-tile static unroll (NT=40 = 6*6 + 4).
// Per tile t: ph1-2 read A(qr0)+B(t), stage B(t+1) [4-phase window];
// ph3-4 read A(qr1), stage A(t+2) [8-phase window >= HBM ~900cyc];
// VMW(4) at tile end drains A(t+1)+B(t+1), keeps A(t+2) in flight.
// Swizzle byte ^= ((row&7)<<4) on pre-swizzled global source + ds_read addr.
#define K1 FIVEH

#define SGA(base, slot, half, kt) do {                                        \
    gload_lds16((base) + (size_t)((half) * 128 + sr0) * K1 + (kt) + sc0,      \
                lds + (slot) * 32768 + (half) * 16384 + db0);                 \
    gload_lds16((base) + (size_t)((half) * 128 + sr1) * K1 + (kt) + sc1,      \
                lds + (slot) * 32768 + (half) * 16384 + db1);                 \
  } while (0)

#define SGB(base, slot, half, kt) do {                                        \
    gload_lds16((base) + (size_t)((half) * 128 + sr0) * K1 + (kt) + sc0,      \
                lds + 98304 + (slot) * 32768 + (half) * 16384 + db0);         \
    gload_lds16((base) + (size_t)((half) * 128 + sr1) * K1 + (kt) + sc1,      \
                lds + 98304 + (slot) * 32768 + (half) * 16384 + db1);         \
  } while (0)

#define LDA1(qr, slot) do { const int _b = (slot) * 32768 + aW + (qr) * 8192; \
    _Pragma("unroll") for (int fm = 0; fm < 4; ++fm)                          \
    _Pragma("unroll") for (int ks = 0; ks < 2; ++ks)                          \
      a[fm][ks] = *(const bf16x8*)(lds + _b + sA[fm][ks]); } while (0)

#define LDB1(dst, qc, slot) do {                                              \
    const int _b = 98304 + (slot) * 32768 + bW + (qc) * 4096;                 \
    _Pragma("unroll") for (int fn = 0; fn < 2; ++fn)                          \
    _Pragma("unroll") for (int ks = 0; ks < 2; ++ks)                          \
      dst[fn][ks] = *(const bf16x8*)(lds + _b + sB[fn][ks]); } while (0)

// SB/SA are literal 0/1 -> dead staging folds away; all slots/kts literal.
#define TILE1(as, bs, AgI, BgI, SB, bsn, ktB, SA, asn, ktA, WAITC) do {       \
    LDA1(0, as); LDB1(b0v, 0, bs);                                            \
    if (SB) SGB(BgI, bsn, 0, ktB);                                            \
    BAR; LGKM0; PRIO(1); MFMA16(0, 0, b0v); PRIO(0); BAR;                     \
    LDB1(b1v, 1, bs);                                                         \
    if (SB) SGB(BgI, bsn, 1, ktB);                                            \
    BAR; LGKM0; PRIO(1); MFMA16(0, 1, b1v); PRIO(0); BAR;                     \
    LDA1(1, as);                                                              \
    if (SA) SGA(AgI, asn, 0, ktA);                                            \
    BAR; LGKM0; PRIO(1); MFMA16(1, 1, b1v); PRIO(0); BAR;                     \
    if (SA) SGA(AgI, asn, 1, ktA);                                            \
    BAR; LGKM0; PRIO(1); MFMA16(1, 0, b0v); PRIO(0); WAITC; BAR;              \
  } while (0)

__device__ __forceinline__ void gemm1_core(const short* __restrict__ Ag,
                                           const short* __restrict__ Bg,
                                           char* lds, f32x4 (&acc)[8][4],
                                           int tid) {
  const int lane = tid & 63;
  const int wave = tid >> 6;
  const int wm = wave >> 2;        // 0..1 -> rows wm*128..+128
  const int wn = wave & 3;         // 0..3 -> cols wn*64..+64
  const int la = lane & 15;
  const int hi = lane >> 4;

  const int x = (la & 7) << 4;
  int sA[4][2], sB[2][2];
#pragma unroll
  for (int fm = 0; fm < 4; ++fm)
#pragma unroll
    for (int ks = 0; ks < 2; ++ks)
      sA[fm][ks] = (((fm * 16 + la) * 128) + (ks * 32 + hi * 8) * 2) ^ x;
#pragma unroll
  for (int fn = 0; fn < 2; ++fn)
#pragma unroll
    for (int ks = 0; ks < 2; ++ks)
      sB[fn][ks] = ((((wn & 1) * 64 + fn * 16 + la) * 128) + (ks * 32 + hi * 8) * 2) ^ x;
  const int aW = wm * 16384;
  const int bW = (wn >> 1) * 16384;

  const int db0 = tid * 16, db1 = tid * 16 + 8192;
  const int lb0 = db0 ^ (((db0 >> 7) & 7) << 4);
  const int lb1 = db1 ^ (((db1 >> 7) & 7) << 4);
  const int sr0 = lb0 >> 7, sc0 = (lb0 & 127) >> 1;
  const int sr1 = lb1 >> 7, sc1 = (lb1 & 127) >> 1;

  bf16x8 a[4][2], b0v[2][2], b1v[2][2];

  // prologue: A0(s0), B0(s0) drained; A1(s1) left in flight (VMW(4))
  SGA(Ag, 0, 0, 0); SGA(Ag, 0, 1, 0);
  SGB(Bg, 0, 0, 0); SGB(Bg, 0, 1, 0);
  SGA(Ag, 1, 0, 64); SGA(Ag, 1, 1, 64);
  VMW(4);
  BAR;

  // 36 tiles: 6 iterations x 6 static tiles (slot pattern period 6)
  for (int i = 0; i < 6; ++i) {
    const short* AgI = Ag + i * 384;
    const short* BgI = Bg + i * 384;
    TILE1(0, 0, AgI, BgI, 1, 1,  64, 1, 2, 128, VMW(4));
    TILE1(1, 1, AgI, BgI, 1, 0, 128, 1, 0, 192, VMW(4));
    TILE1(2, 0, AgI, BgI, 1, 1, 192, 1, 1, 256, VMW(4));
    TILE1(0, 1, AgI, BgI, 1, 0, 256, 1, 2, 320, VMW(4));
    TILE1(1, 0, AgI, BgI, 1, 1, 320, 1, 0, 384, VMW(4));
    TILE1(2, 1, AgI, BgI, 1, 0, 384, 1, 1, 448, VMW(4));
  }
  // tiles 36..39 (kt literals absolute)
  TILE1(0, 0, Ag, Bg, 1, 1, 2368, 1, 2, 2432, VMW(4));
  TILE1(1, 1, Ag, Bg, 1, 0, 2432, 1, 0, 2496, VMW(4));
  TILE1(2, 0, Ag, Bg, 1, 1, 2496, 0, 0, 0,    VMW(0));
  TILE1(0, 1, Ag, Bg, 0, 0, 0,    0, 0, 0,    ((void)0));
}

// ---------------- GEMM1: mid = silu(xn @ w1 + b1), bf16 out (compacted rows)
// Chunked row-major tile map: XCD (bid&7) owns contiguous bm-rows for ALL bn.
__global__ __launch_bounds__(512, 1) void gemm1_kernel(
    const short* __restrict__ A, const short* __restrict__ Bt,
    const float* __restrict__ bias, const int* __restrict__ nkeep,
    short* __restrict__ C) {
  const int nbm = (nkeep[0] + 255) >> 8;
  const int local = blockIdx.x >> 3;
  if (local >= nbm) return;
  const int T = (blockIdx.x & 7) * nbm + local;
  const int bm = T >> 3, bn = T & 7;
  __shared__ __align__(16) char lds[163840];
  const int tid = threadIdx.x;
  f32x4 acc[8][4] = {};
  gemm1_core(A + (size_t)bm * 256 * FIVEH, Bt + (size_t)bn * 256 * FIVEH,
             lds, acc, tid);
  const int lane = tid & 63, wave = tid >> 6;
  const int wm = wave >> 2, wn = wave & 3;
  const int la = lane & 15, hi = lane >> 4;
  const int row0 = bm * 256 + wm * 128 + hi * 4;
  const int col0 = bn * 256 + wn * 64 + la;
#pragma unroll
  for (int mi = 0; mi < 8; ++mi)
#pragma unroll
    for (int ni = 0; ni < 4; ++ni) {
      const int col = col0 + ni * 16;
      const float bv = bias[col];
#pragma unroll
      for (int r = 0; r < 4; ++r) {
        const int row = row0 + mi * 16 + r;
        float v = acc[mi][ni][r] + bv;
        float sg = 1.f / (1.f + __expf(-v));
        C[(size_t)row * FOURH + col] = f2bf(v * sg);
      }
    }
}

// ================= GEMM2 core: BM=256 x BN=128, BK=64, 3-slot pipeline ======
#define ASL(s) ((s) * 32768)
#define BSL(s) (98304 + (s) * 16384)

#define STG2(src, ldsoff, kt) do {                                            \
    const short* _s = (src) + (kt);                                          \
    gload_lds16(_s + (size_t)sr0 * 2048 + sc0, lds + (ldsoff) + db0);         \
    gload_lds16(_s + (size_t)sr1 * 2048 + sc1, lds + (ldsoff) + db1);         \
  } while (0)

#define LDA2(slot) do { const int _b = ASL(slot) + aW2;                       \
    _Pragma("unroll") for (int fm = 0; fm < 4; ++fm)                          \
    _Pragma("unroll") for (int ks = 0; ks < 2; ++ks)                          \
      a[fm][ks] = *(const bf16x8*)(lds + _b + sA2[fm][ks]); } while (0)

#define LDB2a(slot) do { const int _b = BSL(slot);                            \
    _Pragma("unroll") for (int fn = 0; fn < 2; ++fn)                          \
    _Pragma("unroll") for (int ks = 0; ks < 2; ++ks)                          \
      b[fn][ks] = *(const bf16x8*)(lds + _b + sB2[fn][ks]); } while (0)

#define LDB2b(slot) do { const int _b = BSL(slot);                            \
    _Pragma("unroll") for (int fn = 2; fn < 4; ++fn)                          \
    _Pragma("unroll") for (int ks = 0; ks < 2; ++ks)                          \
      b[fn][ks] = *(const bf16x8*)(lds + _b + sB2[fn][ks]); } while (0)

#define MFMA2(h) do {                                                         \
    _Pragma("unroll") for (int fm = 0; fm < 4; ++fm)                          \
    _Pragma("unroll") for (int fn = 2*(h); fn < 2*(h)+2; ++fn)                \
    _Pragma("unroll") for (int ks = 0; ks < 2; ++ks)                          \
      acc[fm][fn] = __builtin_amdgcn_mfma_f32_16x16x32_bf16(                  \
          a[fm][ks], b[fn][ks], acc[fm][fn], 0, 0, 0); } while (0)

#define T2(slot, kt, ISSUE, WAITC) do {                                       \
    LDA2(slot); LDB2a(slot);                                                  \
    if (ISSUE) STG2(Ag, ASL(((slot) + 2) % 3), kt);                           \
    BAR; LGKM0; PRIO(1); MFMA2(0); PRIO(0); BAR;                              \
    LDB2b(slot);                                                              \
    if (ISSUE) { STG2(Ag + 128 * 2048, ASL(((slot) + 2) % 3) + 16384, kt);    \
                 STG2(Bg, BSL(((slot) + 2) % 3), kt); }                       \
    BAR; LGKM0; PRIO(1); MFMA2(1); PRIO(0); WAITC; BAR;                       \
  } while (0)

// ---------------- GEMM2 + finalize fused (disjoint outputs, order-free)
__global__ __launch_bounds__(512) void gemm2fin_kernel(
    const short* __restrict__ A, const short* __restrict__ Bt,
    const float* __restrict__ b2, const float* __restrict__ pos,
    const float* __restrict__ sidtab, const int* __restrict__ destv,
    const int* __restrict__ nkeep, const int* __restrict__ counts,
    const float* __restrict__ empty_tok, float* __restrict__ states,
    float* __restrict__ smask) {
  if (blockIdx.x >= 512) {
    // ------- finalize part: grid-stride zeros/empty/smask -------
    const int total = B_ * S_ * M_ * (H_ / 4);  // float4 chunks
    for (int idx = (blockIdx.x - 512) * 512 + threadIdx.x; idx < total;
         idx += 512 * 512) {
      const int row = idx >> 7, c = idx & 127;
      const int gs = row >> 9, m = row & (M_ - 1), s = gs & (S_ - 1);
      const int cnt = counts[gs];
      const bool empty = (cnt == 0);
      const bool filled = m < (cnt < M_ ? cnt : M_);
      if (c == 0) smask[row] = (filled || (empty && m == 0)) ? 1.0f : 0.0f;
      if (filled) continue;  // written by gemm2 scatter
      float4 o = make_float4(0.f, 0.f, 0.f, 0.f);
      if (empty && m == 0) {
        float4 e = ((const float4*)(empty_tok + s * H_))[c];
        float4 pv = ((const float4*)pos)[c];
        float4 sd = ((const float4*)(sidtab + (s + 1) * H_))[c];
        o.x = e.x + pv.x + sd.x;
        o.y = e.y + pv.y + sd.y;
        o.z = e.z + pv.z + sd.z;
        o.w = e.w + pv.w + sd.w;
      }
      ((float4*)(states + (size_t)row * H_))[c] = o;
    }
    return;
  }
  // ------- GEMM2 part: event = mid @ w2 + b2, scatter via destv -------
  const int bn = blockIdx.x & 3;   // N=512 -> 4 col-tiles of 128
  const int bm = blockIdx.x >> 2;
  const int nk = nkeep[0];
  if (bm * 256 >= nk) return;
  __shared__ __align__(16) char lds[147456];
  const int tid = threadIdx.x;
  const int lane = tid & 63, wave = tid >> 6;
  const int wm = wave >> 1;        // 0..3 -> rows wm*64
  const int wn = wave & 1;         // 0..1 -> cols wn*64
  const int la = lane & 15, hi = lane >> 4;
  const short* Ag = A + (size_t)bm * 256 * 2048;
  const short* Bg = Bt + (size_t)bn * 128 * 2048;

  const int x = (la & 7) << 4;
  int sA2[4][2], sB2[4][2];
#pragma unroll
  for (int fm = 0; fm < 4; ++fm)
#pragma unroll
    for (int ks = 0; ks < 2; ++ks)
      sA2[fm][ks] = ((((wm & 1) * 64 + fm * 16 + la) * 128) + (ks * 32 + hi * 8) * 2) ^ x;
#pragma unroll
  for (int fn = 0; fn < 4; ++fn)
#pragma unroll
    for (int ks = 0; ks < 2; ++ks)
      sB2[fn][ks] = (((wn * 64 + fn * 16 + la) * 128) + (ks * 32 + hi * 8) * 2) ^ x;
  const int aW2 = (wm >> 1) * 16384;

  const int db0 = tid * 16, db1 = tid * 16 + 8192;
  const int lb0 = db0 ^ (((db0 >> 7) & 7) << 4);
  const int lb1 = db1 ^ (((db1 >> 7) & 7) << 4);
  const int sr0 = lb0 >> 7, sc0 = (lb0 & 127) >> 1;
  const int sr1 = lb1 >> 7, sc1 = (lb1 & 127) >> 1;

  f32x4 acc[4][4] = {};
  bf16x8 a[4][2], b[4][2];

  STG2(Ag, ASL(0), 0); STG2(Ag + 128 * 2048, ASL(0) + 16384, 0); STG2(Bg, BSL(0), 0);
  STG2(Ag, ASL(1), 64); STG2(Ag + 128 * 2048, ASL(1) + 16384, 64); STG2(Bg, BSL(1), 64);
  VMW(6);
  BAR;
  for (int i = 0; i < 10; ++i) {
    const int kt = i * 192 + 128;
    T2(0, kt, true, VMW(6));
    T2(1, kt + 64, true, VMW(6));
    T2(2, kt + 128, true, VMW(6));
  }
  T2(0, 0, false, VMW(0));
  T2(1, 0, false, ((void)0));

  const int row0 = bm * 256 + wm * 64 + hi * 4;
  const int col0 = bn * 128 + wn * 64 + la;
#pragma unroll
  for (int mi = 0; mi < 4; ++mi) {
#pragma unroll
    for (int r = 0; r < 4; ++r) {
      const int row = row0 + mi * 16 + r;  // compacted row
      if (row >= nk) continue;
      const int dest = destv[row];
      const int slot = dest & (M_ - 1);
      const int gs = dest >> 9;
      const int s = gs & (S_ - 1);
      float* orow = states + (size_t)dest * H_;
#pragma unroll
      for (int n = 0; n < 4; ++n) {
        const int col = col0 + n * 16;
        orow[col] = acc[mi][n][r] + b2[col] + pos[slot * H_ + col] +
                    sidtab[(s + 1) * H_ + col];
      }
    }
  }
}

// ---------------- prep: fused weight transpose+cvt AND scan+compact ----------
// blocks [0,5120): w1 tiles; [5120,6144): w2 tiles; [6144,6272): scan groups.
__global__ __launch_bounds__(256) void prep_kernel(
    const float* __restrict__ w1, short* __restrict__ w1T,
    const float* __restrict__ w2, short* __restrict__ w2T,
    const int* __restrict__ gid, const int* __restrict__ mask,
    int* __restrict__ counts, int* __restrict__ tokidx,
    int* __restrict__ destv, int* __restrict__ nkeep) {
  const int bid = blockIdx.x;
  if (bid < 6144) {
    const float* in;
    short* out;
    int K, N, tt;
    if (bid < 5120) { in = w1; out = w1T; K = FIVEH; N = FOURH; tt = bid; }
    else            { in = w2; out = w2T; K = FOURH; N = H_;   tt = bid - 5120; }
    const int nT = N >> 5;
    const int n0 = (tt % nT) * 32, k0 = (tt / nT) * 32;
    __shared__ float tile[32][33];
    const int tx = threadIdx.x & 31, ty = threadIdx.x >> 5;
#pragma unroll
    for (int i = 0; i < 32; i += 8)
      tile[ty + i][tx] = in[(size_t)(k0 + ty + i) * N + n0 + tx];
    __syncthreads();
#pragma unroll
    for (int i = 0; i < 32; i += 8)
      out[(size_t)(n0 + ty + i) * K + k0 + tx] = f2bf(tile[tx][ty + i]);
    return;
  }
  // ------- scan+compact: per-(b,s) cumsum -> counts + direct compaction ----
  const int grp = bid - 6144;
  const int b = grp >> 3;
  const int s = grp & 7;
  const int g = s + 1;
  const int base = b * L_;
  const int t = threadIdx.x;
  int loc = 0, sum = 0;
  const int l0 = t * 8;
#pragma unroll
  for (int j = 0; j < 8; ++j) {
    int l = l0 + j;
    bool mt = (mask[base + l] != 0) && (gid[base + l] == g);
    loc |= (mt ? 1 : 0) << j;
    sum += mt ? 1 : 0;
  }
  __shared__ int sdata[256];
  __shared__ int basep, offs;
  sdata[t] = sum;
  __syncthreads();
  for (int off = 1; off < 256; off <<= 1) {
    int vv = (t >= off) ? sdata[t - off] : 0;
    __syncthreads();
    sdata[t] += vv;
    __syncthreads();
  }
  if (t == 255) {
    const int cnt = sdata[255];
    counts[grp] = cnt;
    const int kc = cnt < M_ ? cnt : M_;
    offs = cnt - kc;  // drop all but last M matches
    basep = atomicAdd(nkeep, kc);
  }
  __syncthreads();
  int run = sdata[t] - sum;  // exclusive prefix
  const int gsM = grp * M_;
#pragma unroll
  for (int j = 0; j < 8; ++j) {
    if ((loc >> j) & 1) {
      run += 1;
      const int slot = run - 1 - offs;
      if (slot >= 0) {
        tokidx[basep + slot] = base + l0 + j;
        destv[basep + slot] = gsM + slot;
      }
    }
  }
}

// ---------------- gather 5 embeddings + LayerNorm -> xn bf16 (compacted rows)
__global__ __launch_bounds__(256) void gather_ln_kernel(
    const int* __restrict__ tokidx, const int* __restrict__ nkeep,
    const int* __restrict__ tok0, const int* __restrict__ tok1,
    const int* __restrict__ tok2, const int* __restrict__ tok3,
    const int* __restrict__ tgap,
    const float* __restrict__ emb, const float* __restrict__ gaptab,
    const float* __restrict__ gamma, const float* __restrict__ beta,
    short* __restrict__ xn) {
  const int wid = threadIdx.x >> 6;
  const int l = threadIdx.x & 63;
  const int j = blockIdx.x * 4 + wid;
  const int nk = nkeep[0];
  const int padded = (nk + 255) & ~255;
  if (j >= padded) return;
  short* orow = xn + (size_t)j * FIVEH;
  if (j >= nk) {
    short4 z = make_short4(0, 0, 0, 0);
#pragma unroll
    for (int i = 0; i < 10; ++i) ((short4*)orow)[i * 64 + l] = z;
    return;
  }
  const int token = tokidx[j];
  const int tk0 = tok0[token], tk1 = tok1[token], tk2 = tok2[token],
            tk3 = tok3[token];
  int gi = tgap[token];
  gi = gi < 0 ? 0 : (gi > TG_ ? TG_ : gi);
  const float4* sb[5];
  sb[0] = (const float4*)(emb + (size_t)tk0 * H_);
  sb[1] = (const float4*)(emb + (size_t)tk1 * H_);
  sb[2] = (const float4*)(emb + (size_t)tk2 * H_);
  sb[3] = (const float4*)(emb + (size_t)tk3 * H_);
  sb[4] = (const float4*)(gaptab + (size_t)gi * H_);
  float4 v[10];
  float sum = 0.f, sq = 0.f;
#pragma unroll
  for (int i = 0; i < 10; ++i) {
    const int d4 = i * 64 + l;
    const int seg = i >> 1;
    float4 xv;
    if (seg < 4 || gi != 0) xv = sb[seg][d4 & 127];
    else xv = make_float4(0.f, 0.f, 0.f, 0.f);
    v[i] = xv;
    sum += xv.x + xv.y + xv.z + xv.w;
    sq += xv.x * xv.x + xv.y * xv.y + xv.z * xv.z + xv.w * xv.w;
  }
#pragma unroll
  for (int s = 32; s; s >>= 1) {
    sum += __shfl_xor(sum, s, 64);
    sq += __shfl_xor(sq, s, 64);
  }
  const float mu = sum * (1.f / FIVEH);
  const float var = sq * (1.f / FIVEH) - mu * mu;
  const float rs = rsqrtf(var + 1e-5f);
#pragma unroll
  for (int i = 0; i < 10; ++i) {
    const int d4 = i * 64 + l;
    const float4 g4 = ((const float4*)gamma)[d4];
    const float4 b4 = ((const float4*)beta)[d4];
    short4 o;
    o.x = f2bf((v[i].x - mu) * rs * g4.x + b4.x);
    o.y = f2bf((v[i].y - mu) * rs * g4.y + b4.y);
    o.z = f2bf((v[i].z - mu) * rs * g4.z + b4.z);
    o.w = f2bf((v[i].w - mu) * rs * g4.w + b4.w);
    ((short4*)orow)[d4] = o;
  }
}

extern "C" void kernel_launch(void* const* d_in, const int* in_sizes, int n_in,
                              void* d_out, int out_size, void* d_ws, size_t ws_size,
                              hipStream_t stream) {
  const int* tok0 = (const int*)d_in[0];
  const int* tok1 = (const int*)d_in[1];
  const int* tok2 = (const int*)d_in[2];
  const int* tok3 = (const int*)d_in[3];
  const int* tgap = (const int*)d_in[4];
  const int* gid = (const int*)d_in[5];
  const int* mask = (const int*)d_in[6];
  const float* emb = (const float*)d_in[7];
  const float* gaptab = (const float*)d_in[8];
  const float* sidtab = (const float*)d_in[9];
  const float* pos = (const float*)d_in[10];
  const float* gamma = (const float*)d_in[11];
  const float* beta = (const float*)d_in[12];
  const float* w1 = (const float*)d_in[13];
  const float* b1 = (const float*)d_in[14];
  const float* w2 = (const float*)d_in[15];
  const float* b2 = (const float*)d_in[16];
  const float* empty_tok = (const float*)d_in[17];

  char* p = (char*)d_ws;
  short* xn = (short*)p;  p += (size_t)NTOK * FIVEH * 2;
  short* mid = (short*)p; p += (size_t)NTOK * FOURH * 2;
  short* w1T = (short*)p; p += (size_t)FOURH * FIVEH * 2;
  short* w2T = (short*)p; p += (size_t)H_ * FOURH * 2;
  int* tokidx = (int*)p;  p += (size_t)NTOK * 4;
  int* destv = (int*)p;   p += (size_t)NTOK * 4;
  int* counts = (int*)p;  p += 512;
  int* nkeep = (int*)p;   p += 512;

  float* states = (float*)d_out;
  float* smask = states + (size_t)B_ * S_ * M_ * H_;

  hipMemsetAsync(nkeep, 0, 4, stream);
  prep_kernel<<<6272, 256, 0, stream>>>(w1, w1T, w2, w2T, gid, mask, counts,
                                        tokidx, destv, nkeep);
  gather_ln_kernel<<<NTOK / 4, 256, 0, stream>>>(tokidx, nkeep, tok0, tok1, tok2,
                                                 tok3, tgap, emb, gaptab, gamma,
                                                 beta, xn);
  gemm1_kernel<<<128 * 8, 512, 0, stream>>>(xn, w1T, b1, nkeep, mid);
  gemm2fin_kernel<<<512 + 512, 512, 0, stream>>>(mid, w2T, b2, pos, sidtab,
                                                 destv, nkeep, counts, empty_tok,
                                                 states, smask);
}

// Round 8
// 259.906 us; speedup vs baseline: 1.1692x; 1.1692x over previous
//
#include <hip/hip_runtime.h>
#include <hip/hip_bf16.h>
#include <stdint.h>

#define B_ 16
#define L_ 2048
#define H_ 512
#define S_ 8
#define M_ 512
#define TG_ 64
#define NTOK (B_ * L_)     // 32768
#define FIVEH (5 * H_)     // 2560
#define FOURH (4 * H_)     // 2048

typedef __attribute__((ext_vector_type(4))) float f32x4;
typedef __attribute__((ext_vector_type(8))) short bf16x8;

__device__ __forceinline__ short f2bf(float f) {
  unsigned u = __builtin_bit_cast(unsigned, f);
  unsigned r = (u + 0x7FFFu + ((u >> 16) & 1u)) >> 16;
  return (short)r;
}

__device__ __forceinline__ void gload_lds16(const void* g, void* l) {
  __builtin_amdgcn_global_load_lds(
      (const __attribute__((address_space(1))) unsigned int*)g,
      (__attribute__((address_space(3))) unsigned int*)l, 16, 0, 0);
}

#define BAR __builtin_amdgcn_s_barrier()
#define LGKM0 do { asm volatile("s_waitcnt lgkmcnt(0)" ::: "memory"); \
                   __builtin_amdgcn_sched_barrier(0); } while (0)
#define VMW(n) asm volatile("s_waitcnt vmcnt(" #n ")" ::: "memory")
#define PRIO(p) __builtin_amdgcn_s_setprio(p)

// ================= 256x256 8-phase GEMM core (m201-style, PROVEN r4) ========
// LDS map (128 KiB): A: slot*32768 + half*16384 ; B: 65536 + slot*32768 +
// half*16384. half-tile = 128x64 bf16 = 16384 B. Swizzle byte ^= ((row&7)<<4)
// on pre-swizzled global source + ds_read addr (LDS dest linear, rule #21).
// Windows: A staged 1 tile ahead (4 phases), B staged 2 tiles ahead (8).
// VMW(4) at tile end drains exactly {B(t+1), A(t+1)}, keeps B(t+2) in flight.

#define STAGE(src, isB, slot, half, kt) do {                                  \
    const short* _s = (src) + (size_t)((half) * 128) * K + (kt);              \
    const int _o = ((isB) ? 65536 : 0) + (slot) * 32768 + (half) * 16384;     \
    gload_lds16(_s + (size_t)sr0 * K + sc0, lds + _o + db0);                  \
    gload_lds16(_s + (size_t)sr1 * K + sc1, lds + _o + db1);                  \
  } while (0)

#define LDA(qr, slot) do { const int _b = (slot) * 32768 + aW + (qr) * 8192;  \
    _Pragma("unroll") for (int fm = 0; fm < 4; ++fm)                          \
    _Pragma("unroll") for (int ks = 0; ks < 2; ++ks)                          \
      a[fm][ks] = *(const bf16x8*)(lds + _b + sA[fm][ks]); } while (0)

#define LDB(dst, qc, slot) do { const int _b = (slot) * 32768 + bW + (qc) * 4096; \
    _Pragma("unroll") for (int fn = 0; fn < 2; ++fn)                          \
    _Pragma("unroll") for (int ks = 0; ks < 2; ++ks)                          \
      dst[fn][ks] = *(const bf16x8*)(lds + _b + sB[fn][ks]); } while (0)

#define MFMA16(qr, qc, bs) do {                                               \
    _Pragma("unroll") for (int fm = 0; fm < 4; ++fm)                          \
    _Pragma("unroll") for (int fn = 0; fn < 2; ++fn)                          \
    _Pragma("unroll") for (int ks = 0; ks < 2; ++ks)                          \
      acc[(qr)*4+fm][(qc)*2+fn] = __builtin_amdgcn_mfma_f32_16x16x32_bf16(    \
          a[fm][ks], bs[fn][ks], acc[(qr)*4+fm][(qc)*2+fn], 0, 0, 0); } while (0)

template<int K>
__device__ __forceinline__ void gemm_core(const short* __restrict__ Ag,
                                          const short* __restrict__ Bg,
                                          char* lds, f32x4 (&acc)[8][4],
                                          int tid) {
  constexpr int NITER = K / 128;   // 2 K-tiles (BK=64) per iteration
  const int lane = tid & 63;
  const int wave = tid >> 6;
  const int wm = wave >> 2;        // 0..1 -> rows wm*128..+128
  const int wn = wave & 3;         // 0..3 -> cols wn*64..+64
  const int la = lane & 15;
  const int hi = lane >> 4;

  const int x = (la & 7) << 4;
  int sA[4][2], sB[2][2];
#pragma unroll
  for (int fm = 0; fm < 4; ++fm)
#pragma unroll
    for (int ks = 0; ks < 2; ++ks)
      sA[fm][ks] = (((fm * 16 + la) * 128) + (ks * 32 + hi * 8) * 2) ^ x;
#pragma unroll
  for (int fn = 0; fn < 2; ++fn)
#pragma unroll
    for (int ks = 0; ks < 2; ++ks)
      sB[fn][ks] = ((((wn & 1) * 64 + fn * 16 + la) * 128) + (ks * 32 + hi * 8) * 2) ^ x;
  const int aW = wm * 16384;
  const int bW = 65536 + (wn >> 1) * 16384;

  const int db0 = tid * 16, db1 = tid * 16 + 8192;
  const int lb0 = db0 ^ (((db0 >> 7) & 7) << 4);
  const int lb1 = db1 ^ (((db1 >> 7) & 7) << 4);
  const int sr0 = lb0 >> 7, sc0 = (lb0 & 127) >> 1;
  const int sr1 = lb1 >> 7, sc1 = (lb1 & 127) >> 1;

  bf16x8 a[4][2], b0v[2][2], b1v[2][2];

  STAGE(Bg, 1, 0, 0, 0); STAGE(Bg, 1, 0, 1, 0);
  STAGE(Ag, 0, 0, 0, 0); STAGE(Ag, 0, 0, 1, 0);
  STAGE(Bg, 1, 1, 0, 64); STAGE(Bg, 1, 1, 1, 64);
  VMW(0);
  BAR;

  for (int i = 0; i < NITER - 1; ++i) {
    const int kt1 = (2 * i + 1) * 64, kt2 = kt1 + 64, kt3 = kt1 + 128;
    LDA(0, 0); LDB(b0v, 0, 0); STAGE(Ag, 0, 1, 0, kt1);
    BAR; LGKM0; PRIO(1); MFMA16(0, 0, b0v); PRIO(0); BAR;
    LDB(b1v, 1, 0); STAGE(Ag, 0, 1, 1, kt1);
    BAR; LGKM0; PRIO(1); MFMA16(0, 1, b1v); PRIO(0); BAR;
    LDA(1, 0); STAGE(Bg, 1, 0, 0, kt2);
    BAR; LGKM0; PRIO(1); MFMA16(1, 1, b1v); PRIO(0); BAR;
    STAGE(Bg, 1, 0, 1, kt2);
    BAR; LGKM0; PRIO(1); MFMA16(1, 0, b0v); PRIO(0); VMW(4); BAR;
    LDA(0, 1); LDB(b0v, 0, 1); STAGE(Ag, 0, 0, 0, kt2);
    BAR; LGKM0; PRIO(1); MFMA16(0, 0, b0v); PRIO(0); BAR;
    LDB(b1v, 1, 1); STAGE(Ag, 0, 0, 1, kt2);
    BAR; LGKM0; PRIO(1); MFMA16(0, 1, b1v); PRIO(0); BAR;
    LDA(1, 1); STAGE(Bg, 1, 1, 0, kt3);
    BAR; LGKM0; PRIO(1); MFMA16(1, 1, b1v); PRIO(0); BAR;
    STAGE(Bg, 1, 1, 1, kt3);
    BAR; LGKM0; PRIO(1); MFMA16(1, 0, b0v); PRIO(0); VMW(4); BAR;
  }
  {
    const int kt1 = (2 * (NITER - 1) + 1) * 64;
    LDA(0, 0); LDB(b0v, 0, 0); STAGE(Ag, 0, 1, 0, kt1);
    BAR; LGKM0; PRIO(1); MFMA16(0, 0, b0v); PRIO(0); BAR;
    LDB(b1v, 1, 0); STAGE(Ag, 0, 1, 1, kt1);
    BAR; LGKM0; PRIO(1); MFMA16(0, 1, b1v); PRIO(0); BAR;
    LDA(1, 0);
    BAR; LGKM0; PRIO(1); MFMA16(1, 1, b1v); PRIO(0); BAR;
    BAR; LGKM0; PRIO(1); MFMA16(1, 0, b0v); PRIO(0); VMW(0); BAR;
    LDA(0, 1); LDB(b0v, 0, 1);
    BAR; LGKM0; PRIO(1); MFMA16(0, 0, b0v); PRIO(0); BAR;
    LDB(b1v, 1, 1);
    BAR; LGKM0; PRIO(1); MFMA16(0, 1, b1v); PRIO(0); BAR;
    LDA(1, 1);
    BAR; LGKM0; PRIO(1); MFMA16(1, 1, b1v); PRIO(0); BAR;
    BAR; LGKM0; PRIO(1); MFMA16(1, 0, b0v); PRIO(0);
  }
}

// ---------------- GEMM1: mid = silu(xn @ w1 + b1), bf16 out (compacted rows)
// Chunked row-major tile map: XCD (bid&7) owns contiguous bm-rows for ALL bn.
__global__ __launch_bounds__(512, 2) void gemm1_kernel(
    const short* __restrict__ A, const short* __restrict__ Bt,
    const float* __restrict__ bias, const int* __restrict__ nkeep,
    short* __restrict__ C) {
  const int nbm = (nkeep[0] + 255) >> 8;
  const int local = blockIdx.x >> 3;
  if (local >= nbm) return;
  const int T = (blockIdx.x & 7) * nbm + local;
  const int bm = T >> 3, bn = T & 7;
  __shared__ __align__(16) char lds[131072];
  const int tid = threadIdx.x;
  f32x4 acc[8][4] = {};
  gemm_core<FIVEH>(A + (size_t)bm * 256 * FIVEH, Bt + (size_t)bn * 256 * FIVEH,
                   lds, acc, tid);
  const int lane = tid & 63, wave = tid >> 6;
  const int wm = wave >> 2, wn = wave & 3;
  const int la = lane & 15, hi = lane >> 4;
  const int row0 = bm * 256 + wm * 128 + hi * 4;
  const int col0 = bn * 256 + wn * 64 + la;
#pragma unroll
  for (int mi = 0; mi < 8; ++mi)
#pragma unroll
    for (int ni = 0; ni < 4; ++ni) {
      const int col = col0 + ni * 16;
      const float bv = bias[col];
#pragma unroll
      for (int r = 0; r < 4; ++r) {
        const int row = row0 + mi * 16 + r;
        float v = acc[mi][ni][r] + bv;
        float sg = 1.f / (1.f + __expf(-v));
        C[(size_t)row * FOURH + col] = f2bf(v * sg);
      }
    }
}

// ================= GEMM2 core: BM=256 x BN=128, BK=64, 3-slot pipeline ======
#define ASL(s) ((s) * 32768)
#define BSL(s) (98304 + (s) * 16384)

#define STG2(src, ldsoff, kt) do {                                            \
    const short* _s = (src) + (kt);                                          \
    gload_lds16(_s + (size_t)sr0 * 2048 + sc0, lds + (ldsoff) + db0);         \
    gload_lds16(_s + (size_t)sr1 * 2048 + sc1, lds + (ldsoff) + db1);         \
  } while (0)

#define LDA2(slot) do { const int _b = ASL(slot) + aW2;                       \
    _Pragma("unroll") for (int fm = 0; fm < 4; ++fm)                          \
    _Pragma("unroll") for (int ks = 0; ks < 2; ++ks)                          \
      a[fm][ks] = *(const bf16x8*)(lds + _b + sA2[fm][ks]); } while (0)

#define LDB2a(slot) do { const int _b = BSL(slot);                            \
    _Pragma("unroll") for (int fn = 0; fn < 2; ++fn)                          \
    _Pragma("unroll") for (int ks = 0; ks < 2; ++ks)                          \
      b[fn][ks] = *(const bf16x8*)(lds + _b + sB2[fn][ks]); } while (0)

#define LDB2b(slot) do { const int _b = BSL(slot);                            \
    _Pragma("unroll") for (int fn = 2; fn < 4; ++fn)                          \
    _Pragma("unroll") for (int ks = 0; ks < 2; ++ks)                          \
      b[fn][ks] = *(const bf16x8*)(lds + _b + sB2[fn][ks]); } while (0)

#define MFMA2(h) do {                                                         \
    _Pragma("unroll") for (int fm = 0; fm < 4; ++fm)                          \
    _Pragma("unroll") for (int fn = 2*(h); fn < 2*(h)+2; ++fn)                \
    _Pragma("unroll") for (int ks = 0; ks < 2; ++ks)                          \
      acc[fm][fn] = __builtin_amdgcn_mfma_f32_16x16x32_bf16(                  \
          a[fm][ks], b[fn][ks], acc[fm][fn], 0, 0, 0); } while (0)

#define T2(slot, kt, ISSUE, WAITC) do {                                       \
    LDA2(slot); LDB2a(slot);                                                  \
    if (ISSUE) STG2(Ag, ASL(((slot) + 2) % 3), kt);                           \
    BAR; LGKM0; PRIO(1); MFMA2(0); PRIO(0); BAR;                              \
    LDB2b(slot);                                                              \
    if (ISSUE) { STG2(Ag + 128 * 2048, ASL(((slot) + 2) % 3) + 16384, kt);    \
                 STG2(Bg, BSL(((slot) + 2) % 3), kt); }                       \
    BAR; LGKM0; PRIO(1); MFMA2(1); PRIO(0); WAITC; BAR;                       \
  } while (0)

// ---------------- GEMM2 + finalize fused (disjoint outputs, order-free)
__global__ __launch_bounds__(512) void gemm2fin_kernel(
    const short* __restrict__ A, const short* __restrict__ Bt,
    const float* __restrict__ b2, const float* __restrict__ pos,
    const float* __restrict__ sidtab, const int* __restrict__ destv,
    const int* __restrict__ nkeep, const int* __restrict__ counts,
    const float* __restrict__ empty_tok, float* __restrict__ states,
    float* __restrict__ smask) {
  if (blockIdx.x >= 512) {
    // ------- finalize part: grid-stride zeros/empty/smask -------
    const int total = B_ * S_ * M_ * (H_ / 4);  // float4 chunks
    for (int idx = (blockIdx.x - 512) * 512 + threadIdx.x; idx < total;
         idx += 512 * 512) {
      const int row = idx >> 7, c = idx & 127;
      const int gs = row >> 9, m = row & (M_ - 1), s = gs & (S_ - 1);
      const int cnt = counts[gs];
      const bool empty = (cnt == 0);
      const bool filled = m < (cnt < M_ ? cnt : M_);
      if (c == 0) smask[row] = (filled || (empty && m == 0)) ? 1.0f : 0.0f;
      if (filled) continue;  // written by gemm2 scatter
      float4 o = make_float4(0.f, 0.f, 0.f, 0.f);
      if (empty && m == 0) {
        float4 e = ((const float4*)(empty_tok + s * H_))[c];
        float4 pv = ((const float4*)pos)[c];
        float4 sd = ((const float4*)(sidtab + (s + 1) * H_))[c];
        o.x = e.x + pv.x + sd.x;
        o.y = e.y + pv.y + sd.y;
        o.z = e.z + pv.z + sd.z;
        o.w = e.w + pv.w + sd.w;
      }
      ((float4*)(states + (size_t)row * H_))[c] = o;
    }
    return;
  }
  // ------- GEMM2 part: event = mid @ w2 + b2, scatter via destv -------
  // Bijective chunked XCD map: each XCD owns contiguous bm range x all 4 bn
  // -> each mid A-panel (1 MB) HBM-fetched once, 4x L2-reuse.
  const int nk = nkeep[0];
  const int ntile = ((nk + 255) >> 8) << 2;   // nbm2 * 4
  const int q = ntile >> 3, r = ntile & 7;
  const int xg = blockIdx.x & 7, idx = blockIdx.x >> 3;
  const int cntx = q + (xg < r ? 1 : 0);
  if (idx >= cntx) return;
  const int T = xg * q + (xg < r ? xg : r) + idx;
  const int bm = T >> 2, bn = T & 3;
  __shared__ __align__(16) char lds[147456];
  const int tid = threadIdx.x;
  const int lane = tid & 63, wave = tid >> 6;
  const int wm = wave >> 1;        // 0..3 -> rows wm*64
  const int wn = wave & 1;         // 0..1 -> cols wn*64
  const int la = lane & 15, hi = lane >> 4;
  const short* Ag = A + (size_t)bm * 256 * 2048;
  const short* Bg = Bt + (size_t)bn * 128 * 2048;

  const int x = (la & 7) << 4;
  int sA2[4][2], sB2[4][2];
#pragma unroll
  for (int fm = 0; fm < 4; ++fm)
#pragma unroll
    for (int ks = 0; ks < 2; ++ks)
      sA2[fm][ks] = ((((wm & 1) * 64 + fm * 16 + la) * 128) + (ks * 32 + hi * 8) * 2) ^ x;
#pragma unroll
  for (int fn = 0; fn < 4; ++fn)
#pragma unroll
    for (int ks = 0; ks < 2; ++ks)
      sB2[fn][ks] = (((wn * 64 + fn * 16 + la) * 128) + (ks * 32 + hi * 8) * 2) ^ x;
  const int aW2 = (wm >> 1) * 16384;

  const int db0 = tid * 16, db1 = tid * 16 + 8192;
  const int lb0 = db0 ^ (((db0 >> 7) & 7) << 4);
  const int lb1 = db1 ^ (((db1 >> 7) & 7) << 4);
  const int sr0 = lb0 >> 7, sc0 = (lb0 & 127) >> 1;
  const int sr1 = lb1 >> 7, sc1 = (lb1 & 127) >> 1;

  f32x4 acc[4][4] = {};
  bf16x8 a[4][2], b[4][2];

  STG2(Ag, ASL(0), 0); STG2(Ag + 128 * 2048, ASL(0) + 16384, 0); STG2(Bg, BSL(0), 0);
  STG2(Ag, ASL(1), 64); STG2(Ag + 128 * 2048, ASL(1) + 16384, 64); STG2(Bg, BSL(1), 64);
  VMW(6);
  BAR;
  for (int i = 0; i < 10; ++i) {
    const int kt = i * 192 + 128;
    T2(0, kt, true, VMW(6));
    T2(1, kt + 64, true, VMW(6));
    T2(2, kt + 128, true, VMW(6));
  }
  T2(0, 0, false, VMW(0));
  T2(1, 0, false, ((void)0));

  const int row0 = bm * 256 + wm * 64 + hi * 4;
  const int col0 = bn * 128 + wn * 64 + la;
#pragma unroll
  for (int mi = 0; mi < 4; ++mi) {
#pragma unroll
    for (int r2 = 0; r2 < 4; ++r2) {
      const int row = row0 + mi * 16 + r2;  // compacted row
      if (row >= nk) continue;
      const int dest = destv[row];
      const int slot = dest & (M_ - 1);
      const int gs = dest >> 9;
      const int s = gs & (S_ - 1);
      float* orow = states + (size_t)dest * H_;
#pragma unroll
      for (int n = 0; n < 4; ++n) {
        const int col = col0 + n * 16;
        orow[col] = acc[mi][n][r2] + b2[col] + pos[slot * H_ + col] +
                    sidtab[(s + 1) * H_ + col];
      }
    }
  }
}

// ---------------- prep: fused weight transpose+cvt AND scan+compact ----------
// blocks [0,5120): w1 tiles; [5120,6144): w2 tiles; [6144,6272): scan groups.
__global__ __launch_bounds__(256) void prep_kernel(
    const float* __restrict__ w1, short* __restrict__ w1T,
    const float* __restrict__ w2, short* __restrict__ w2T,
    const int* __restrict__ gid, const int* __restrict__ mask,
    int* __restrict__ counts, int* __restrict__ tokidx,
    int* __restrict__ destv, int* __restrict__ nkeep) {
  const int bid = blockIdx.x;
  if (bid < 6144) {
    const float* in;
    short* out;
    int K, N, tt;
    if (bid < 5120) { in = w1; out = w1T; K = FIVEH; N = FOURH; tt = bid; }
    else            { in = w2; out = w2T; K = FOURH; N = H_;   tt = bid - 5120; }
    const int nT = N >> 5;
    const int n0 = (tt % nT) * 32, k0 = (tt / nT) * 32;
    __shared__ float tile[32][33];
    const int tx = threadIdx.x & 31, ty = threadIdx.x >> 5;
#pragma unroll
    for (int i = 0; i < 32; i += 8)
      tile[ty + i][tx] = in[(size_t)(k0 + ty + i) * N + n0 + tx];
    __syncthreads();
#pragma unroll
    for (int i = 0; i < 32; i += 8)
      out[(size_t)(n0 + ty + i) * K + k0 + tx] = f2bf(tile[tx][ty + i]);
    return;
  }
  // ------- scan+compact: per-(b,s) cumsum -> counts + direct compaction ----
  const int grp = bid - 6144;
  const int b = grp >> 3;
  const int s = grp & 7;
  const int g = s + 1;
  const int base = b * L_;
  const int t = threadIdx.x;
  int loc = 0, sum = 0;
  const int l0 = t * 8;
#pragma unroll
  for (int j = 0; j < 8; ++j) {
    int l = l0 + j;
    bool mt = (mask[base + l] != 0) && (gid[base + l] == g);
    loc |= (mt ? 1 : 0) << j;
    sum += mt ? 1 : 0;
  }
  __shared__ int sdata[256];
  __shared__ int basep, offs;
  sdata[t] = sum;
  __syncthreads();
  for (int off = 1; off < 256; off <<= 1) {
    int vv = (t >= off) ? sdata[t - off] : 0;
    __syncthreads();
    sdata[t] += vv;
    __syncthreads();
  }
  if (t == 255) {
    const int cnt = sdata[255];
    counts[grp] = cnt;
    const int kc = cnt < M_ ? cnt : M_;
    offs = cnt - kc;  // drop all but last M matches
    basep = atomicAdd(nkeep, kc);
  }
  __syncthreads();
  int run = sdata[t] - sum;  // exclusive prefix
  const int gsM = grp * M_;
#pragma unroll
  for (int j = 0; j < 8; ++j) {
    if ((loc >> j) & 1) {
      run += 1;
      const int slot = run - 1 - offs;
      if (slot >= 0) {
        tokidx[basep + slot] = base + l0 + j;
        destv[basep + slot] = gsM + slot;
      }
    }
  }
}

// ---------------- gather 5 embeddings + LayerNorm -> xn bf16 (compacted rows)
__global__ __launch_bounds__(256) void gather_ln_kernel(
    const int* __restrict__ tokidx, const int* __restrict__ nkeep,
    const int* __restrict__ tok0, const int* __restrict__ tok1,
    const int* __restrict__ tok2, const int* __restrict__ tok3,
    const int* __restrict__ tgap,
    const float* __restrict__ emb, const float* __restrict__ gaptab,
    const float* __restrict__ gamma, const float* __restrict__ beta,
    short* __restrict__ xn) {
  const int wid = threadIdx.x >> 6;
  const int l = threadIdx.x & 63;
  const int j = blockIdx.x * 4 + wid;
  const int nk = nkeep[0];
  const int padded = (nk + 255) & ~255;
  if (j >= padded) return;
  short* orow = xn + (size_t)j * FIVEH;
  if (j >= nk) {
    short4 z = make_short4(0, 0, 0, 0);
#pragma unroll
    for (int i = 0; i < 10; ++i) ((short4*)orow)[i * 64 + l] = z;
    return;
  }
  const int token = tokidx[j];
  const int tk0 = tok0[token], tk1 = tok1[token], tk2 = tok2[token],
            tk3 = tok3[token];
  int gi = tgap[token];
  gi = gi < 0 ? 0 : (gi > TG_ ? TG_ : gi);
  const float4* sb[5];
  sb[0] = (const float4*)(emb + (size_t)tk0 * H_);
  sb[1] = (const float4*)(emb + (size_t)tk1 * H_);
  sb[2] = (const float4*)(emb + (size_t)tk2 * H_);
  sb[3] = (const float4*)(emb + (size_t)tk3 * H_);
  sb[4] = (const float4*)(gaptab + (size_t)gi * H_);
  float4 v[10];
  float sum = 0.f, sq = 0.f;
#pragma unroll
  for (int i = 0; i < 10; ++i) {
    const int d4 = i * 64 + l;
    const int seg = i >> 1;
    float4 xv;
    if (seg < 4 || gi != 0) xv = sb[seg][d4 & 127];
    else xv = make_float4(0.f, 0.f, 0.f, 0.f);
    v[i] = xv;
    sum += xv.x + xv.y + xv.z + xv.w;
    sq += xv.x * xv.x + xv.y * xv.y + xv.z * xv.z + xv.w * xv.w;
  }
#pragma unroll
  for (int s = 32; s; s >>= 1) {
    sum += __shfl_xor(sum, s, 64);
    sq += __shfl_xor(sq, s, 64);
  }
  const float mu = sum * (1.f / FIVEH);
  const float var = sq * (1.f / FIVEH) - mu * mu;
  const float rs = rsqrtf(var + 1e-5f);
#pragma unroll
  for (int i = 0; i < 10; ++i) {
    const int d4 = i * 64 + l;
    const float4 g4 = ((const float4*)gamma)[d4];
    const float4 b4 = ((const float4*)beta)[d4];
    short4 o;
    o.x = f2bf((v[i].x - mu) * rs * g4.x + b4.x);
    o.y = f2bf((v[i].y - mu) * rs * g4.y + b4.y);
    o.z = f2bf((v[i].z - mu) * rs * g4.z + b4.z);
    o.w = f2bf((v[i].w - mu) * rs * g4.w + b4.w);
    ((short4*)orow)[d4] = o;
  }
}

extern "C" void kernel_launch(void* const* d_in, const int* in_sizes, int n_in,
                              void* d_out, int out_size, void* d_ws, size_t ws_size,
                              hipStream_t stream) {
  const int* tok0 = (const int*)d_in[0];
  const int* tok1 = (const int*)d_in[1];
  const int* tok2 = (const int*)d_in[2];
  const int* tok3 = (const int*)d_in[3];
  const int* tgap = (const int*)d_in[4];
  const int* gid = (const int*)d_in[5];
  const int* mask = (const int*)d_in[6];
  const float* emb = (const float*)d_in[7];
  const float* gaptab = (const float*)d_in[8];
  const float* sidtab = (const float*)d_in[9];
  const float* pos = (const float*)d_in[10];
  const float* gamma = (const float*)d_in[11];
  const float* beta = (const float*)d_in[12];
  const float* w1 = (const float*)d_in[13];
  const float* b1 = (const float*)d_in[14];
  const float* w2 = (const float*)d_in[15];
  const float* b2 = (const float*)d_in[16];
  const float* empty_tok = (const float*)d_in[17];

  char* p = (char*)d_ws;
  short* xn = (short*)p;  p += (size_t)NTOK * FIVEH * 2;
  short* mid = (short*)p; p += (size_t)NTOK * FOURH * 2;
  short* w1T = (short*)p; p += (size_t)FOURH * FIVEH * 2;
  short* w2T = (short*)p; p += (size_t)H_ * FOURH * 2;
  int* tokidx = (int*)p;  p += (size_t)NTOK * 4;
  int* destv = (int*)p;   p += (size_t)NTOK * 4;
  int* counts = (int*)p;  p += 512;
  int* nkeep = (int*)p;   p += 512;

  float* states = (float*)d_out;
  float* smask = states + (size_t)B_ * S_ * M_ * H_;

  hipMemsetAsync(nkeep, 0, 4, stream);
  prep_kernel<<<6272, 256, 0, stream>>>(w1, w1T, w2, w2T, gid, mask, counts,
                                        tokidx, destv, nkeep);
  gather_ln_kernel<<<NTOK / 4, 256, 0, stream>>>(tokidx, nkeep, tok0, tok1, tok2,
                                                 tok3, tgap, emb, gaptab, gamma,
                                                 beta, xn);
  gemm1_kernel<<<128 * 8, 512, 0, stream>>>(xn, w1T, b1, nkeep, mid);
  gemm2fin_kernel<<<512 + 512, 512, 0, stream>>>(mid, w2T, b2, pos, sidtab,
                                                 destv, nkeep, counts, empty_tok,
                                                 states, smask);
}

// Round 9
// 252.508 us; speedup vs baseline: 1.2034x; 1.0293x over previous
//
#include <hip/hip_runtime.h>
#include <hip/hip_bf16.h>
#include <stdint.h>

#define B_ 16
#define L_ 2048
#define H_ 512
#define S_ 8
#define M_ 512
#define TG_ 64
#define NTOK (B_ * L_)     // 32768
#define FIVEH (5 * H_)     // 2560
#define FOURH (4 * H_)     // 2048

typedef __attribute__((ext_vector_type(4))) float f32x4;
typedef __attribute__((ext_vector_type(8))) short bf16x8;

__device__ __forceinline__ short f2bf(float f) {
  unsigned u = __builtin_bit_cast(unsigned, f);
  unsigned r = (u + 0x7FFFu + ((u >> 16) & 1u)) >> 16;
  return (short)r;
}

__device__ __forceinline__ void gload_lds16(const void* g, void* l) {
  __builtin_amdgcn_global_load_lds(
      (const __attribute__((address_space(1))) unsigned int*)g,
      (__attribute__((address_space(3))) unsigned int*)l, 16, 0, 0);
}

#define BAR __builtin_amdgcn_s_barrier()
#define LGKM0 do { asm volatile("s_waitcnt lgkmcnt(0)" ::: "memory"); \
                   __builtin_amdgcn_sched_barrier(0); } while (0)
#define VMW(n) asm volatile("s_waitcnt vmcnt(" #n ")" ::: "memory")
#define PRIO(p) __builtin_amdgcn_s_setprio(p)

// ================= 256x256 8-phase GEMM core (m201-style, PROVEN r4/r8) =====
// LDS map (128 KiB): A: slot*32768 + half*16384 ; B: 65536 + slot*32768 +
// half*16384. half-tile = 128x64 bf16 = 16384 B. Swizzle byte ^= ((row&7)<<4)
// on pre-swizzled global source + ds_read addr (LDS dest linear, rule #21).

#define STAGE(src, isB, slot, half, kt) do {                                  \
    const short* _s = (src) + (size_t)((half) * 128) * K + (kt);              \
    const int _o = ((isB) ? 65536 : 0) + (slot) * 32768 + (half) * 16384;     \
    gload_lds16(_s + (size_t)sr0 * K + sc0, lds + _o + db0);                  \
    gload_lds16(_s + (size_t)sr1 * K + sc1, lds + _o + db1);                  \
  } while (0)

#define LDA(qr, slot) do { const int _b = (slot) * 32768 + aW + (qr) * 8192;  \
    _Pragma("unroll") for (int fm = 0; fm < 4; ++fm)                          \
    _Pragma("unroll") for (int ks = 0; ks < 2; ++ks)                          \
      a[fm][ks] = *(const bf16x8*)(lds + _b + sA[fm][ks]); } while (0)

#define LDB(dst, qc, slot) do { const int _b = (slot) * 32768 + bW + (qc) * 4096; \
    _Pragma("unroll") for (int fn = 0; fn < 2; ++fn)                          \
    _Pragma("unroll") for (int ks = 0; ks < 2; ++ks)                          \
      dst[fn][ks] = *(const bf16x8*)(lds + _b + sB[fn][ks]); } while (0)

#define MFMA16(qr, qc, bs) do {                                               \
    _Pragma("unroll") for (int fm = 0; fm < 4; ++fm)                          \
    _Pragma("unroll") for (int fn = 0; fn < 2; ++fn)                          \
    _Pragma("unroll") for (int ks = 0; ks < 2; ++ks)                          \
      acc[(qr)*4+fm][(qc)*2+fn] = __builtin_amdgcn_mfma_f32_16x16x32_bf16(    \
          a[fm][ks], bs[fn][ks], acc[(qr)*4+fm][(qc)*2+fn], 0, 0, 0); } while (0)

template<int K>
__device__ __forceinline__ void gemm_core(const short* __restrict__ Ag,
                                          const short* __restrict__ Bg,
                                          char* lds, f32x4 (&acc)[8][4],
                                          int tid) {
  constexpr int NITER = K / 128;   // 2 K-tiles (BK=64) per iteration
  const int lane = tid & 63;
  const int wave = tid >> 6;
  const int wm = wave >> 2;        // 0..1 -> rows wm*128..+128
  const int wn = wave & 3;         // 0..3 -> cols wn*64..+64
  const int la = lane & 15;
  const int hi = lane >> 4;

  const int x = (la & 7) << 4;
  int sA[4][2], sB[2][2];
#pragma unroll
  for (int fm = 0; fm < 4; ++fm)
#pragma unroll
    for (int ks = 0; ks < 2; ++ks)
      sA[fm][ks] = (((fm * 16 + la) * 128) + (ks * 32 + hi * 8) * 2) ^ x;
#pragma unroll
  for (int fn = 0; fn < 2; ++fn)
#pragma unroll
    for (int ks = 0; ks < 2; ++ks)
      sB[fn][ks] = ((((wn & 1) * 64 + fn * 16 + la) * 128) + (ks * 32 + hi * 8) * 2) ^ x;
  const int aW = wm * 16384;
  const int bW = 65536 + (wn >> 1) * 16384;

  const int db0 = tid * 16, db1 = tid * 16 + 8192;
  const int lb0 = db0 ^ (((db0 >> 7) & 7) << 4);
  const int lb1 = db1 ^ (((db1 >> 7) & 7) << 4);
  const int sr0 = lb0 >> 7, sc0 = (lb0 & 127) >> 1;
  const int sr1 = lb1 >> 7, sc1 = (lb1 & 127) >> 1;

  bf16x8 a[4][2], b0v[2][2], b1v[2][2];

  STAGE(Bg, 1, 0, 0, 0); STAGE(Bg, 1, 0, 1, 0);
  STAGE(Ag, 0, 0, 0, 0); STAGE(Ag, 0, 0, 1, 0);
  STAGE(Bg, 1, 1, 0, 64); STAGE(Bg, 1, 1, 1, 64);
  VMW(0);
  BAR;

  for (int i = 0; i < NITER - 1; ++i) {
    const int kt1 = (2 * i + 1) * 64, kt2 = kt1 + 64, kt3 = kt1 + 128;
    LDA(0, 0); LDB(b0v, 0, 0); STAGE(Ag, 0, 1, 0, kt1);
    BAR; LGKM0; PRIO(1); MFMA16(0, 0, b0v); PRIO(0); BAR;
    LDB(b1v, 1, 0); STAGE(Ag, 0, 1, 1, kt1);
    BAR; LGKM0; PRIO(1); MFMA16(0, 1, b1v); PRIO(0); BAR;
    LDA(1, 0); STAGE(Bg, 1, 0, 0, kt2);
    BAR; LGKM0; PRIO(1); MFMA16(1, 1, b1v); PRIO(0); BAR;
    STAGE(Bg, 1, 0, 1, kt2);
    BAR; LGKM0; PRIO(1); MFMA16(1, 0, b0v); PRIO(0); VMW(4); BAR;
    LDA(0, 1); LDB(b0v, 0, 1); STAGE(Ag, 0, 0, 0, kt2);
    BAR; LGKM0; PRIO(1); MFMA16(0, 0, b0v); PRIO(0); BAR;
    LDB(b1v, 1, 1); STAGE(Ag, 0, 0, 1, kt2);
    BAR; LGKM0; PRIO(1); MFMA16(0, 1, b1v); PRIO(0); BAR;
    LDA(1, 1); STAGE(Bg, 1, 1, 0, kt3);
    BAR; LGKM0; PRIO(1); MFMA16(1, 1, b1v); PRIO(0); BAR;
    STAGE(Bg, 1, 1, 1, kt3);
    BAR; LGKM0; PRIO(1); MFMA16(1, 0, b0v); PRIO(0); VMW(4); BAR;
  }
  {
    const int kt1 = (2 * (NITER - 1) + 1) * 64;
    LDA(0, 0); LDB(b0v, 0, 0); STAGE(Ag, 0, 1, 0, kt1);
    BAR; LGKM0; PRIO(1); MFMA16(0, 0, b0v); PRIO(0); BAR;
    LDB(b1v, 1, 0); STAGE(Ag, 0, 1, 1, kt1);
    BAR; LGKM0; PRIO(1); MFMA16(0, 1, b1v); PRIO(0); BAR;
    LDA(1, 0);
    BAR; LGKM0; PRIO(1); MFMA16(1, 1, b1v); PRIO(0); BAR;
    BAR; LGKM0; PRIO(1); MFMA16(1, 0, b0v); PRIO(0); VMW(0); BAR;
    LDA(0, 1); LDB(b0v, 0, 1);
    BAR; LGKM0; PRIO(1); MFMA16(0, 0, b0v); PRIO(0); BAR;
    LDB(b1v, 1, 1);
    BAR; LGKM0; PRIO(1); MFMA16(0, 1, b1v); PRIO(0); BAR;
    LDA(1, 1);
    BAR; LGKM0; PRIO(1); MFMA16(1, 1, b1v); PRIO(0); BAR;
    BAR; LGKM0; PRIO(1); MFMA16(1, 0, b0v); PRIO(0);
  }
}

// ---------------- GEMM1 + finalize fused: GEMM blocks (local < nbm) compute
// mid = silu(xn @ w1 + b1); surplus blocks do the zero-fill/empty/smask work
// on CUs idled by the GEMM tail round. Disjoint outputs (mid vs states/smask).
__global__ __launch_bounds__(512, 2) void gemm1fin_kernel(
    const short* __restrict__ A, const short* __restrict__ Bt,
    const float* __restrict__ bias, const int* __restrict__ nkeep,
    short* __restrict__ C, const int* __restrict__ counts,
    const float* __restrict__ empty_tok, const float* __restrict__ pos,
    const float* __restrict__ sidtab, float* __restrict__ states,
    float* __restrict__ smask) {
  const int nbm = (nkeep[0] + 255) >> 8;
  const int local = blockIdx.x >> 3;
  if (local >= nbm) {
    // ------- finalize: grid-stride zeros/empty/smask over surplus blocks ----
    const int fstart = nbm << 3;
    const int fcount = (int)gridDim.x - fstart;   // >= 64 always (grid 1088)
    const int fid = (int)blockIdx.x - fstart;
    const int total = B_ * S_ * M_ * (H_ / 4);    // float4 chunks
    for (int idx = fid * 512 + (int)threadIdx.x; idx < total;
         idx += fcount * 512) {
      const int row = idx >> 7, c = idx & 127;
      const int gs = row >> 9, m = row & (M_ - 1), s = gs & (S_ - 1);
      const int cnt = counts[gs];
      const bool empty = (cnt == 0);
      const bool filled = m < (cnt < M_ ? cnt : M_);
      if (c == 0) smask[row] = (filled || (empty && m == 0)) ? 1.0f : 0.0f;
      if (filled) continue;  // written by gemm2 scatter (next launch)
      float4 o = make_float4(0.f, 0.f, 0.f, 0.f);
      if (empty && m == 0) {
        float4 e = ((const float4*)(empty_tok + s * H_))[c];
        float4 pv = ((const float4*)pos)[c];
        float4 sd = ((const float4*)(sidtab + (s + 1) * H_))[c];
        o.x = e.x + pv.x + sd.x;
        o.y = e.y + pv.y + sd.y;
        o.z = e.z + pv.z + sd.z;
        o.w = e.w + pv.w + sd.w;
      }
      ((float4*)(states + (size_t)row * H_))[c] = o;
    }
    return;
  }
  // ------- GEMM path (byte-identical schedule to r8) ------------------------
  // Chunked row-major tile map: XCD (bid&7) owns contiguous bm-rows for ALL bn.
  const int T = (blockIdx.x & 7) * nbm + local;
  const int bm = T >> 3, bn = T & 7;
  __shared__ __align__(16) char lds[131072];
  const int tid = threadIdx.x;
  f32x4 acc[8][4] = {};
  gemm_core<FIVEH>(A + (size_t)bm * 256 * FIVEH, Bt + (size_t)bn * 256 * FIVEH,
                   lds, acc, tid);
  const int lane = tid & 63, wave = tid >> 6;
  const int wm = wave >> 2, wn = wave & 3;
  const int la = lane & 15, hi = lane >> 4;
  const int row0 = bm * 256 + wm * 128 + hi * 4;
  const int col0 = bn * 256 + wn * 64 + la;
#pragma unroll
  for (int mi = 0; mi < 8; ++mi)
#pragma unroll
    for (int ni = 0; ni < 4; ++ni) {
      const int col = col0 + ni * 16;
      const float bv = bias[col];
#pragma unroll
      for (int r = 0; r < 4; ++r) {
        const int row = row0 + mi * 16 + r;
        float v = acc[mi][ni][r] + bv;
        float sg = 1.f / (1.f + __expf(-v));
        C[(size_t)row * FOURH + col] = f2bf(v * sg);
      }
    }
}

// ================= GEMM2 core: BM=256 x BN=128, BK=64, 3-slot pipeline ======
#define ASL(s) ((s) * 32768)
#define BSL(s) (98304 + (s) * 16384)

#define STG2(src, ldsoff, kt) do {                                            \
    const short* _s = (src) + (kt);                                          \
    gload_lds16(_s + (size_t)sr0 * 2048 + sc0, lds + (ldsoff) + db0);         \
    gload_lds16(_s + (size_t)sr1 * 2048 + sc1, lds + (ldsoff) + db1);         \
  } while (0)

#define LDA2(slot) do { const int _b = ASL(slot) + aW2;                       \
    _Pragma("unroll") for (int fm = 0; fm < 4; ++fm)                          \
    _Pragma("unroll") for (int ks = 0; ks < 2; ++ks)                          \
      a[fm][ks] = *(const bf16x8*)(lds + _b + sA2[fm][ks]); } while (0)

#define LDB2a(slot) do { const int _b = BSL(slot);                            \
    _Pragma("unroll") for (int fn = 0; fn < 2; ++fn)                          \
    _Pragma("unroll") for (int ks = 0; ks < 2; ++ks)                          \
      b[fn][ks] = *(const bf16x8*)(lds + _b + sB2[fn][ks]); } while (0)

#define LDB2b(slot) do { const int _b = BSL(slot);                            \
    _Pragma("unroll") for (int fn = 2; fn < 4; ++fn)                          \
    _Pragma("unroll") for (int ks = 0; ks < 2; ++ks)                          \
      b[fn][ks] = *(const bf16x8*)(lds + _b + sB2[fn][ks]); } while (0)

#define MFMA2(h) do {                                                         \
    _Pragma("unroll") for (int fm = 0; fm < 4; ++fm)                          \
    _Pragma("unroll") for (int fn = 2*(h); fn < 2*(h)+2; ++fn)                \
    _Pragma("unroll") for (int ks = 0; ks < 2; ++ks)                          \
      acc[fm][fn] = __builtin_amdgcn_mfma_f32_16x16x32_bf16(                  \
          a[fm][ks], b[fn][ks], acc[fm][fn], 0, 0, 0); } while (0)

#define T2(slot, kt, ISSUE, WAITC) do {                                       \
    LDA2(slot); LDB2a(slot);                                                  \
    if (ISSUE) STG2(Ag, ASL(((slot) + 2) % 3), kt);                           \
    BAR; LGKM0; PRIO(1); MFMA2(0); PRIO(0); BAR;                              \
    LDB2b(slot);                                                              \
    if (ISSUE) { STG2(Ag + 128 * 2048, ASL(((slot) + 2) % 3) + 16384, kt);    \
                 STG2(Bg, BSL(((slot) + 2) % 3), kt); }                       \
    BAR; LGKM0; PRIO(1); MFMA2(1); PRIO(0); WAITC; BAR;                       \
  } while (0)

// ---------------- GEMM2: event = mid @ w2 + b2, scatter via destv (+pos+sid)
// Bijective chunked XCD map: each XCD owns contiguous bm range x all 4 bn.
__global__ __launch_bounds__(512) void gemm2_kernel(
    const short* __restrict__ A, const short* __restrict__ Bt,
    const float* __restrict__ b2, const float* __restrict__ pos,
    const float* __restrict__ sidtab, const int* __restrict__ destv,
    const int* __restrict__ nkeep, float* __restrict__ states) {
  const int nk = nkeep[0];
  const int ntile = ((nk + 255) >> 8) << 2;   // nbm2 * 4
  const int q = ntile >> 3, r = ntile & 7;
  const int xg = blockIdx.x & 7, idx = blockIdx.x >> 3;
  const int cntx = q + (xg < r ? 1 : 0);
  if (idx >= cntx) return;
  const int T = xg * q + (xg < r ? xg : r) + idx;
  const int bm = T >> 2, bn = T & 3;
  __shared__ __align__(16) char lds[147456];
  const int tid = threadIdx.x;
  const int lane = tid & 63, wave = tid >> 6;
  const int wm = wave >> 1;        // 0..3 -> rows wm*64
  const int wn = wave & 1;         // 0..1 -> cols wn*64
  const int la = lane & 15, hi = lane >> 4;
  const short* Ag = A + (size_t)bm * 256 * 2048;
  const short* Bg = Bt + (size_t)bn * 128 * 2048;

  const int x = (la & 7) << 4;
  int sA2[4][2], sB2[4][2];
#pragma unroll
  for (int fm = 0; fm < 4; ++fm)
#pragma unroll
    for (int ks = 0; ks < 2; ++ks)
      sA2[fm][ks] = ((((wm & 1) * 64 + fm * 16 + la) * 128) + (ks * 32 + hi * 8) * 2) ^ x;
#pragma unroll
  for (int fn = 0; fn < 4; ++fn)
#pragma unroll
    for (int ks = 0; ks < 2; ++ks)
      sB2[fn][ks] = (((wn * 64 + fn * 16 + la) * 128) + (ks * 32 + hi * 8) * 2) ^ x;
  const int aW2 = (wm >> 1) * 16384;

  const int db0 = tid * 16, db1 = tid * 16 + 8192;
  const int lb0 = db0 ^ (((db0 >> 7) & 7) << 4);
  const int lb1 = db1 ^ (((db1 >> 7) & 7) << 4);
  const int sr0 = lb0 >> 7, sc0 = (lb0 & 127) >> 1;
  const int sr1 = lb1 >> 7, sc1 = (lb1 & 127) >> 1;

  f32x4 acc[4][4] = {};
  bf16x8 a[4][2], b[4][2];

  STG2(Ag, ASL(0), 0); STG2(Ag + 128 * 2048, ASL(0) + 16384, 0); STG2(Bg, BSL(0), 0);
  STG2(Ag, ASL(1), 64); STG2(Ag + 128 * 2048, ASL(1) + 16384, 64); STG2(Bg, BSL(1), 64);
  VMW(6);
  BAR;
  for (int i = 0; i < 10; ++i) {
    const int kt = i * 192 + 128;
    T2(0, kt, true, VMW(6));
    T2(1, kt + 64, true, VMW(6));
    T2(2, kt + 128, true, VMW(6));
  }
  T2(0, 0, false, VMW(0));
  T2(1, 0, false, ((void)0));

  const int row0 = bm * 256 + wm * 64 + hi * 4;
  const int col0 = bn * 128 + wn * 64 + la;
#pragma unroll
  for (int mi = 0; mi < 4; ++mi) {
#pragma unroll
    for (int r2 = 0; r2 < 4; ++r2) {
      const int row = row0 + mi * 16 + r2;  // compacted row
      if (row >= nk) continue;
      const int dest = destv[row];
      const int slot = dest & (M_ - 1);
      const int gs = dest >> 9;
      const int s = gs & (S_ - 1);
      float* orow = states + (size_t)dest * H_;
#pragma unroll
      for (int n = 0; n < 4; ++n) {
        const int col = col0 + n * 16;
        orow[col] = acc[mi][n][r2] + b2[col] + pos[slot * H_ + col] +
                    sidtab[(s + 1) * H_ + col];
      }
    }
  }
}

// ---------------- scan+compact: per-(b,s) cumsum -> counts + direct compaction
__global__ __launch_bounds__(256) void scan_kernel(
    const int* __restrict__ gid, const int* __restrict__ mask,
    int* __restrict__ counts, int* __restrict__ tokidx,
    int* __restrict__ destv, int* __restrict__ nkeep) {
  const int grp = blockIdx.x;
  const int b = grp >> 3;
  const int s = grp & 7;
  const int g = s + 1;
  const int base = b * L_;
  const int t = threadIdx.x;
  int loc = 0, sum = 0;
  const int l0 = t * 8;
#pragma unroll
  for (int j = 0; j < 8; ++j) {
    int l = l0 + j;
    bool mt = (mask[base + l] != 0) && (gid[base + l] == g);
    loc |= (mt ? 1 : 0) << j;
    sum += mt ? 1 : 0;
  }
  __shared__ int sdata[256];
  __shared__ int basep, offs;
  sdata[t] = sum;
  __syncthreads();
  for (int off = 1; off < 256; off <<= 1) {
    int vv = (t >= off) ? sdata[t - off] : 0;
    __syncthreads();
    sdata[t] += vv;
    __syncthreads();
  }
  if (t == 255) {
    const int cnt = sdata[255];
    counts[grp] = cnt;
    const int kc = cnt < M_ ? cnt : M_;
    offs = cnt - kc;  // drop all but last M matches
    basep = atomicAdd(nkeep, kc);
  }
  __syncthreads();
  int run = sdata[t] - sum;  // exclusive prefix
  const int gsM = grp * M_;
#pragma unroll
  for (int j = 0; j < 8; ++j) {
    if ((loc >> j) & 1) {
      run += 1;
      const int slot = run - 1 - offs;
      if (slot >= 0) {
        tokidx[basep + slot] = base + l0 + j;
        destv[basep + slot] = gsM + slot;
      }
    }
  }
}

// ---------------- gather+LN (compacted rows) AND weight transpose, one launch
// blocks [0,8192): gather_ln ; [8192,14336): w1/w2 transpose tiles.
__global__ __launch_bounds__(256) void gather_tr_kernel(
    const int* __restrict__ tokidx, const int* __restrict__ nkeep,
    const int* __restrict__ tok0, const int* __restrict__ tok1,
    const int* __restrict__ tok2, const int* __restrict__ tok3,
    const int* __restrict__ tgap,
    const float* __restrict__ emb, const float* __restrict__ gaptab,
    const float* __restrict__ gamma, const float* __restrict__ beta,
    short* __restrict__ xn,
    const float* __restrict__ w1, short* __restrict__ w1T,
    const float* __restrict__ w2, short* __restrict__ w2T) {
  if (blockIdx.x >= 8192) {
    // ------- weight transpose + bf16 cvt -------
    const int bid = blockIdx.x - 8192;
    const float* in;
    short* out;
    int K, N, tt;
    if (bid < 5120) { in = w1; out = w1T; K = FIVEH; N = FOURH; tt = bid; }
    else            { in = w2; out = w2T; K = FOURH; N = H_;   tt = bid - 5120; }
    const int nT = N >> 5;
    const int n0 = (tt % nT) * 32, k0 = (tt / nT) * 32;
    __shared__ float tile[32][33];
    const int tx = threadIdx.x & 31, ty = threadIdx.x >> 5;
#pragma unroll
    for (int i = 0; i < 32; i += 8)
      tile[ty + i][tx] = in[(size_t)(k0 + ty + i) * N + n0 + tx];
    __syncthreads();
#pragma unroll
    for (int i = 0; i < 32; i += 8)
      out[(size_t)(n0 + ty + i) * K + k0 + tx] = f2bf(tile[tx][ty + i]);
    return;
  }
  // ------- gather 5 embeddings + LayerNorm -> xn bf16 -------
  const int wid = threadIdx.x >> 6;
  const int l = threadIdx.x & 63;
  const int j = blockIdx.x * 4 + wid;
  const int nk = nkeep[0];
  const int padded = (nk + 255) & ~255;
  if (j >= padded) return;
  short* orow = xn + (size_t)j * FIVEH;
  if (j >= nk) {
    short4 z = make_short4(0, 0, 0, 0);
#pragma unroll
    for (int i = 0; i < 10; ++i) ((short4*)orow)[i * 64 + l] = z;
    return;
  }
  const int token = tokidx[j];
  const int tk0 = tok0[token], tk1 = tok1[token], tk2 = tok2[token],
            tk3 = tok3[token];
  int gi = tgap[token];
  gi = gi < 0 ? 0 : (gi > TG_ ? TG_ : gi);
  const float4* sb[5];
  sb[0] = (const float4*)(emb + (size_t)tk0 * H_);
  sb[1] = (const float4*)(emb + (size_t)tk1 * H_);
  sb[2] = (const float4*)(emb + (size_t)tk2 * H_);
  sb[3] = (const float4*)(emb + (size_t)tk3 * H_);
  sb[4] = (const float4*)(gaptab + (size_t)gi * H_);
  float4 v[10];
  float sum = 0.f, sq = 0.f;
#pragma unroll
  for (int i = 0; i < 10; ++i) {
    const int d4 = i * 64 + l;
    const int seg = i >> 1;
    float4 xv;
    if (seg < 4 || gi != 0) xv = sb[seg][d4 & 127];
    else xv = make_float4(0.f, 0.f, 0.f, 0.f);
    v[i] = xv;
    sum += xv.x + xv.y + xv.z + xv.w;
    sq += xv.x * xv.x + xv.y * xv.y + xv.z * xv.z + xv.w * xv.w;
  }
#pragma unroll
  for (int s = 32; s; s >>= 1) {
    sum += __shfl_xor(sum, s, 64);
    sq += __shfl_xor(sq, s, 64);
  }
  const float mu = sum * (1.f / FIVEH);
  const float var = sq * (1.f / FIVEH) - mu * mu;
  const float rs = rsqrtf(var + 1e-5f);
#pragma unroll
  for (int i = 0; i < 10; ++i) {
    const int d4 = i * 64 + l;
    const float4 g4 = ((const float4*)gamma)[d4];
    const float4 b4 = ((const float4*)beta)[d4];
    short4 o;
    o.x = f2bf((v[i].x - mu) * rs * g4.x + b4.x);
    o.y = f2bf((v[i].y - mu) * rs * g4.y + b4.y);
    o.z = f2bf((v[i].z - mu) * rs * g4.z + b4.z);
    o.w = f2bf((v[i].w - mu) * rs * g4.w + b4.w);
    ((short4*)orow)[d4] = o;
  }
}

extern "C" void kernel_launch(void* const* d_in, const int* in_sizes, int n_in,
                              void* d_out, int out_size, void* d_ws, size_t ws_size,
                              hipStream_t stream) {
  const int* tok0 = (const int*)d_in[0];
  const int* tok1 = (const int*)d_in[1];
  const int* tok2 = (const int*)d_in[2];
  const int* tok3 = (const int*)d_in[3];
  const int* tgap = (const int*)d_in[4];
  const int* gid = (const int*)d_in[5];
  const int* mask = (const int*)d_in[6];
  const float* emb = (const float*)d_in[7];
  const float* gaptab = (const float*)d_in[8];
  const float* sidtab = (const float*)d_in[9];
  const float* pos = (const float*)d_in[10];
  const float* gamma = (const float*)d_in[11];
  const float* beta = (const float*)d_in[12];
  const float* w1 = (const float*)d_in[13];
  const float* b1 = (const float*)d_in[14];
  const float* w2 = (const float*)d_in[15];
  const float* b2 = (const float*)d_in[16];
  const float* empty_tok = (const float*)d_in[17];

  char* p = (char*)d_ws;
  short* xn = (short*)p;  p += (size_t)NTOK * FIVEH * 2;
  short* mid = (short*)p; p += (size_t)NTOK * FOURH * 2;
  short* w1T = (short*)p; p += (size_t)FOURH * FIVEH * 2;
  short* w2T = (short*)p; p += (size_t)H_ * FOURH * 2;
  int* tokidx = (int*)p;  p += (size_t)NTOK * 4;
  int* destv = (int*)p;   p += (size_t)NTOK * 4;
  int* counts = (int*)p;  p += 512;
  int* nkeep = (int*)p;   p += 512;

  float* states = (float*)d_out;
  float* smask = states + (size_t)B_ * S_ * M_ * H_;

  hipMemsetAsync(nkeep, 0, 4, stream);
  scan_kernel<<<B_ * S_, 256, 0, stream>>>(gid, mask, counts, tokidx, destv,
                                           nkeep);
  gather_tr_kernel<<<8192 + 6144, 256, 0, stream>>>(
      tokidx, nkeep, tok0, tok1, tok2, tok3, tgap, emb, gaptab, gamma, beta,
      xn, w1, w1T, w2, w2T);
  gemm1fin_kernel<<<1024 + 64, 512, 0, stream>>>(xn, w1T, b1, nkeep, mid,
                                                 counts, empty_tok, pos, sidtab,
                                                 states, smask);
  gemm2_kernel<<<512, 512, 0, stream>>>(mid, w2T, b2, pos, sidtab, destv,
                                        nkeep, states);
}